// Round 15
// baseline (190.192 us; speedup 1.0000x reference)
//
#include <hip/hip_runtime.h>
#include <hip/hip_cooperative_groups.h>

namespace cg = cooperative_groups;

// Problem constants (fixed by the reference).
#define BATCH 16384
#define DIN   128
#define HIDN  16
#define NNODE 255
#define NLEAF 256

typedef _Float16 half8 __attribute__((ext_vector_type(8)));
typedef float   float4v __attribute__((ext_vector_type(4)));

// ---------------- single cooperative kernel: pack + MLP + tree ----------------
// Grid 256 blocks (exactly 1/CU: VGPR~84, LDS 83 KB, 768 thr -> co-residency
// guaranteed) x 12 waves. R9/R11 measured each kernel boundary at ~5-8 us; this
// removes the last one.
// Stage A (pre-sync): block b<255 packs W1[b] -> w1p (old k_pack W1 branch,
//   staged through the then-unused sp buffer); every block packs its own 64 rows
//   of x -> LDS xq (R10-proven mapping). threadfence + grid.sync() makes w1p
//   visible across XCDs.
// Stage B: R8-proven body. Phase 1: waves split nodes mod 12, ping-pong operand
//   prefetch, 16 MFMA -> f32 relu-FMA -> 3-shuffle butterfly -> sigmoid ->
//   sp[batch][node] (clamp-to-254 dup writes bitwise identical, benign).
//   Phase 2: block barrier, tree scan rows r=wv+12k from LDS, coalesced stores.
__global__ __launch_bounds__(768, 3) void k_all(const float* __restrict__ x, const float* __restrict__ w1,
                                                const float* __restrict__ b1, const float* __restrict__ w2,
                                                const float* __restrict__ b2, const float* __restrict__ leaf,
                                                half8* __restrict__ w1p,
                                                float* __restrict__ h_out, float* __restrict__ pp_out,
                                                float* __restrict__ p_out, float* __restrict__ nr_out) {
    __shared__ float sp[64][261];                 // 66.8 KB; stage-A W1 staging + phase-1/2 probs
    __shared__ half8 xq[16][64];                  // 16 KB x B-fragments
    int tid  = threadIdx.x;
    int wv   = tid >> 6;                          // 0..11
    int lane = tid & 63;
    int q    = lane >> 4;

    // ---- stage A1: inline x -> f16 fragment pack (own 64 rows) ----
    for (int g = tid; g < 1024; g += 768) {
        int f  = g >> 6, ln = g & 63;
        int t  = f >> 2, kc = f & 3;
        const float4* src = (const float4*)(x + (size_t)(blockIdx.x * 64 + t * 16 + (ln & 15)) * DIN
                                              + kc * 32 + ((ln >> 4) * 8));
        float4 v0 = src[0], v1 = src[1];
        half8 v;
        v[0] = (_Float16)v0.x; v[1] = (_Float16)v0.y; v[2] = (_Float16)v0.z; v[3] = (_Float16)v0.w;
        v[4] = (_Float16)v1.x; v[5] = (_Float16)v1.y; v[6] = (_Float16)v1.z; v[7] = (_Float16)v1.w;
        xq[f][ln] = v;
    }

    // ---- stage A2: block b < 255 packs W1[b] via sp staging (threads 0..255) ----
    {
        float* w = &sp[0][0];                     // 2176-float staging area
        bool packw = (blockIdx.x < NNODE) && (tid < 256);
        float4 a0, a1;
        if (packw) {
            const float4* srcw = (const float4*)(w1 + (size_t)blockIdx.x * (DIN * HIDN)) + tid * 2;
            a0 = srcw[0]; a1 = srcw[1];
            int base = tid * 8;
#pragma unroll
            for (int e = 0; e < 4; ++e) {
                int idx0 = base + e, idx1 = base + 4 + e;
                w[(idx0 >> 4) * 17 + (idx0 & 15)] = (&a0.x)[e];
                w[(idx1 >> 4) * 17 + (idx1 & 15)] = (&a1.x)[e];
            }
        }
        __syncthreads();                          // uniform: all 768 threads
        if (packw) {
            int L  = tid & 63;
            int kc = tid >> 6;
            int m  = L & 15;
            int k0 = kc * 32 + (L >> 4) * 8;
            half8 v;
#pragma unroll
            for (int j = 0; j < 8; ++j) v[j] = (_Float16)w[(k0 + j) * 17 + m];
            w1p[(size_t)blockIdx.x * 256 + tid] = v;
        }
    }
    __threadfence();                              // release w1p writes device-wide
    cg::this_grid().sync();                       // all blocks: w1p ready

    // ---- load B-fragments from xq: 16 half8 = 64 VGPRs ----
    half8 bq[4][4];
#pragma unroll
    for (int t = 0; t < 4; ++t)
#pragma unroll
        for (int kc = 0; kc < 4; ++kc)
            bq[t][kc] = xq[t * 4 + kc][lane];
    asm volatile("" ::: "memory");

    // ---- phase 1: MLP over this wave's nodes (n == wv mod 12), ping-pong ----
    half8  aA[4], aB[4];
    float4 b1A, b1B, w2A, w2B;
    float  b2A, b2B;

    int nA = wv;
#pragma unroll
    for (int kc = 0; kc < 4; ++kc) aA[kc] = w1p[(size_t)(nA * 4 + kc) * 64 + lane];
    b1A = ((const float4*)(b1 + nA * HIDN))[q];
    w2A = ((const float4*)(w2 + nA * HIDN))[q];
    b2A = b2[nA];
    {
        int nB = nA + 12;
#pragma unroll
        for (int kc = 0; kc < 4; ++kc) aB[kc] = w1p[(size_t)(nB * 4 + kc) * 64 + lane];
        b1B = ((const float4*)(b1 + nB * HIDN))[q];
        w2B = ((const float4*)(w2 + nB * HIDN))[q];
        b2B = b2[nB];
    }

// One node: 16 MFMA -> f32 relu-FMA partials -> prefetch -> butterfly -> sigmoid -> LDS.
// Butterfly: lane(q,b) ends with logit of tile t==q, batch row q*16+b == lane.
#define MLP_BODY(AS, B1S, W2S, B2S, NODE, PREN)                                            \
    do {                                                                                   \
        float4v acc0 = {B1S.x, B1S.y, B1S.z, B1S.w};                                       \
        float4v acc1 = acc0, acc2 = acc0, acc3 = acc0;                                     \
        _Pragma("unroll") for (int kc = 0; kc < 4; ++kc) {                                 \
            acc0 = __builtin_amdgcn_mfma_f32_16x16x32_f16(AS[kc], bq[0][kc], acc0, 0, 0, 0);\
            acc1 = __builtin_amdgcn_mfma_f32_16x16x32_f16(AS[kc], bq[1][kc], acc1, 0, 0, 0);\
            acc2 = __builtin_amdgcn_mfma_f32_16x16x32_f16(AS[kc], bq[2][kc], acc2, 0, 0, 0);\
            acc3 = __builtin_amdgcn_mfma_f32_16x16x32_f16(AS[kc], bq[3][kc], acc3, 0, 0, 0);\
        }                                                                                  \
        float s0 = fmaf(fmaxf(acc0[0], 0.f), W2S.x, fmaf(fmaxf(acc0[1], 0.f), W2S.y,       \
                   fmaf(fmaxf(acc0[2], 0.f), W2S.z, fmaxf(acc0[3], 0.f) * W2S.w)));        \
        float s1 = fmaf(fmaxf(acc1[0], 0.f), W2S.x, fmaf(fmaxf(acc1[1], 0.f), W2S.y,       \
                   fmaf(fmaxf(acc1[2], 0.f), W2S.z, fmaxf(acc1[3], 0.f) * W2S.w)));        \
        float s2 = fmaf(fmaxf(acc2[0], 0.f), W2S.x, fmaf(fmaxf(acc2[1], 0.f), W2S.y,       \
                   fmaf(fmaxf(acc2[2], 0.f), W2S.z, fmaxf(acc2[3], 0.f) * W2S.w)));        \
        float s3 = fmaf(fmaxf(acc3[0], 0.f), W2S.x, fmaf(fmaxf(acc3[1], 0.f), W2S.y,       \
                   fmaf(fmaxf(acc3[2], 0.f), W2S.z, fmaxf(acc3[3], 0.f) * W2S.w)));        \
        float b2c = B2S;                                                                   \
        _Pragma("unroll") for (int kc = 0; kc < 4; ++kc)                                   \
            AS[kc] = w1p[(size_t)((PREN) * 4 + kc) * 64 + lane];                           \
        B1S = ((const float4*)(b1 + (PREN) * HIDN))[q];                                    \
        W2S = ((const float4*)(w2 + (PREN) * HIDN))[q];                                    \
        B2S = b2[PREN];                                                                    \
        int q1 = q & 1, q2 = q & 2;                                                        \
        float a01 = q1 ? s1 : s0, c01 = q1 ? s0 : s1;                                      \
        a01 += __shfl_xor(c01, 16, 64);                                                    \
        float a23 = q1 ? s3 : s2, c23 = q1 ? s2 : s3;                                      \
        a23 += __shfl_xor(c23, 16, 64);                                                    \
        float e = q2 ? a23 : a01, f = q2 ? a01 : a23;                                      \
        e += __shfl_xor(f, 32, 64);                                                        \
        float lg = e + b2c;                                                                \
        sp[lane][NODE] =                                                                   \
            __builtin_amdgcn_rcpf(1.f + __builtin_amdgcn_exp2f(-1.44269504088896f * lg));  \
    } while (0)

    // 11 ping-pong iterations cover nodes {wv + 12j, j=0..21}; indices past 254
    // clamp to 254 (recomputed with node-254's own operands -> identical value).
    for (int ii = 0; ii < 11; ++ii) {
        int pA = nA + 24; pA = pA > 254 ? 254 : pA;
        MLP_BODY(aA, b1A, w2A, b2A, nA, pA);          // nA <= 252 always
        int nB = nA + 12; nB = nB > 254 ? 254 : nB;
        int pB = nA + 36; pB = pB > 254 ? 254 : pB;
        MLP_BODY(aB, b1B, w2B, b2B, nB, pB);
        nA += 24;
    }
#undef MLP_BODY
    __syncthreads();

    // ---- phase 2: tree scan, rows r = wv, wv+12, ... straight from LDS ----
    const float4 lf = *(const float4*)(leaf + 4 * lane);
    for (int r = wv; r < 64; r += 12) {
        int b = blockIdx.x * 64 + r;
        const float* P = &sp[r][0];
        float* nr = nr_out + (size_t)b * NNODE;

        // p_out copy, coalesced
#pragma unroll
        for (int c = 0; c < 4; ++c) {
            int idx = c * 64 + lane;
            if (idx < NNODE)
                p_out[(size_t)b * NNODE + idx] = P[idx];
        }

        float pref = 1.f;
#pragma unroll
        for (int l = 0; l < 6; ++l) {
            if ((lane & ((1 << (6 - l)) - 1)) == 0)
                nr[(1 << l) - 1 + (lane >> (6 - l))] = pref;
            float pv  = P[(1 << l) - 1 + (lane >> (6 - l))];
            int  bit  = (lane >> (5 - l)) & 1;
            pref *= bit ? pv : (1.f - pv);
        }
        nr[63 + lane] = pref;
        float p6 = P[63 + lane];
        float pl = pref * (1.f - p6);
        float pr = pref * p6;
        nr[127 + 2 * lane] = pl;
        nr[128 + 2 * lane] = pr;
        float p7a = P[127 + 2 * lane];
        float p7b = P[128 + 2 * lane];
        float4v pp;
        pp[0] = pl * (1.f - p7a);
        pp[1] = pl * p7a;
        pp[2] = pr * (1.f - p7b);
        pp[3] = pr * p7b;
        *(float4v*)(pp_out + (size_t)b * NLEAF + 4 * lane) = pp;
        float hs = pp[0] * lf.x + pp[1] * lf.y + pp[2] * lf.z + pp[3] * lf.w;
#pragma unroll
        for (int off = 1; off < 64; off <<= 1) hs += __shfl_xor(hs, off, 64);
        if (lane == 0) h_out[b] = hs;
    }
}

extern "C" void kernel_launch(void* const* d_in, const int* in_sizes, int n_in,
                              void* d_out, int out_size, void* d_ws, size_t ws_size,
                              hipStream_t stream) {
    const float* x    = (const float*)d_in[0];
    const float* W1   = (const float*)d_in[1];
    const float* b1   = (const float*)d_in[2];
    const float* W2   = (const float*)d_in[3];
    const float* b2   = (const float*)d_in[4];
    const float* leaf = (const float*)d_in[5];

    float* out    = (float*)d_out;
    float* h_out  = out;                                   // [16384]
    float* pp_out = out + BATCH;                           // [16384*256]
    float* p_out  = pp_out + (size_t)BATCH * NLEAF;        // [16384*255]
    float* nr_out = p_out + (size_t)BATCH * NNODE;         // [16384*255]

    // workspace: ~1 MB w1p only
    half8* w1p = (half8*)d_ws;

    void* args[] = {(void*)&x, (void*)&W1, (void*)&b1, (void*)&W2, (void*)&b2, (void*)&leaf,
                    (void*)&w1p, (void*)&h_out, (void*)&pp_out, (void*)&p_out, (void*)&nr_out};
    hipLaunchCooperativeKernel((void*)k_all, dim3(256), dim3(768), args, 0, stream);
}

// Round 16
// 106.558 us; speedup vs baseline: 1.7849x; 1.7849x over previous
//
#include <hip/hip_runtime.h>

// Problem constants (fixed by the reference).
#define BATCH 16384
#define DIN   128
#define HIDN  16
#define NNODE 255
#define NLEAF 256

typedef _Float16 half8 __attribute__((ext_vector_type(8)));
typedef float   float4v __attribute__((ext_vector_type(4)));

// ---------------- combined pack kernel ----------------
// blocks 0..1023: pack x -> f16 B-operand fragments
//   lane L holds B[k=(L>>4)*8+j][n=L&15] (n=batch, k=din); ws: [bt][kc][lane] half8
// blocks 1024..1278: pack W1[n] -> f16 A-operand fragments (LDS-staged)
//   lane L holds A[m=L&15][k=(L>>4)*8+j] (m=hidden, k=din)
__global__ __launch_bounds__(256) void k_pack(const float* __restrict__ x, const float* __restrict__ w1,
                                              half8* __restrict__ xp, half8* __restrict__ w1p) {
    __shared__ float w[DIN * 17];
    int t = threadIdx.x;
    if (blockIdx.x < 1024) {
        int gid  = blockIdx.x * 256 + t;
        int lane = gid & 63;
        int kc   = (gid >> 6) & 3;
        int bt   = gid >> 8;
        const float4* src = (const float4*)(x + (size_t)(bt * 16 + (lane & 15)) * DIN + kc * 32 + ((lane >> 4) * 8));
        float4 v0 = src[0], v1 = src[1];
        half8 v;
        v[0] = (_Float16)v0.x; v[1] = (_Float16)v0.y; v[2] = (_Float16)v0.z; v[3] = (_Float16)v0.w;
        v[4] = (_Float16)v1.x; v[5] = (_Float16)v1.y; v[6] = (_Float16)v1.z; v[7] = (_Float16)v1.w;
        xp[gid] = v;
    } else {
        int n = blockIdx.x - 1024;
        const float4* src = (const float4*)(w1 + (size_t)n * (DIN * HIDN)) + t * 2;
        float4 a0 = src[0], a1 = src[1];
        int base = t * 8;
#pragma unroll
        for (int e = 0; e < 4; ++e) {
            int idx0 = base + e, idx1 = base + 4 + e;
            w[(idx0 >> 4) * 17 + (idx0 & 15)] = (&a0.x)[e];
            w[(idx1 >> 4) * 17 + (idx1 & 15)] = (&a1.x)[e];
        }
        __syncthreads();
        int L  = t & 63;
        int kc = t >> 6;
        int m  = L & 15;
        int k0 = kc * 32 + (L >> 4) * 8;
        half8 v;
#pragma unroll
        for (int j = 0; j < 8; ++j) v[j] = (_Float16)w[(k0 + j) * 17 + m];
        w1p[(size_t)n * 256 + t] = v;
    }
}

// ---------------- fused MLP + tree kernel, 64 rows / block, 12 waves ----------------
// Grid 256 blocks (1/CU) x 768 threads = 12 waves = 3 waves/SIMD. Per-CU w1p
// traffic ~1 MB (each fragment read by exactly one wave); LDS 66.6 KB.
// BEST-MEASURED CONFIGURATION (106.58 us total, R8 bench) — reverted to verbatim
// after R9-R15 variants (attribution split, inline x-pack, phase-1 p_out stores,
// clamp-free padding, cooperative single-launch) all measured worse or null.
// Phase 1: waves split nodes mod 12; per node 16 MFMA -> f32 relu-FMA ->
// 3-shuffle butterfly -> sigmoid -> sp[batch][node]. Ping-pong operand prefetch;
// clamp-to-254 dup writes are bitwise identical (benign).
// Phase 2: one barrier, tree-scan rows r = wv+12k straight from LDS.
__global__ __launch_bounds__(768, 3) void k_fused(const half8* __restrict__ xp, const half8* __restrict__ w1p,
                                                  const float* __restrict__ b1, const float* __restrict__ w2,
                                                  const float* __restrict__ b2, const float* __restrict__ leaf,
                                                  float* __restrict__ h_out, float* __restrict__ pp_out,
                                                  float* __restrict__ p_out, float* __restrict__ nr_out) {
    __shared__ float sp[64][260];                 // 66.6 KB
    int wv   = threadIdx.x >> 6;                  // 0..11
    int lane = threadIdx.x & 63;
    int q    = lane >> 4;
    int bt0  = blockIdx.x * 4;                    // four 16-row tiles

    // B-fragments for all 4 tiles (identical in every wave): 16 half8 = 64 VGPRs
    half8 bq[4][4];
#pragma unroll
    for (int t = 0; t < 4; ++t)
#pragma unroll
        for (int kc = 0; kc < 4; ++kc)
            bq[t][kc] = xp[(size_t)((bt0 + t) * 4 + kc) * 64 + lane];
    asm volatile("" ::: "memory");

    // ---- phase 1: MLP over this wave's nodes (n == wv mod 12), ping-pong ----
    half8  aA[4], aB[4];
    float4 b1A, b1B, w2A, w2B;
    float  b2A, b2B;

    int nA = wv;
#pragma unroll
    for (int kc = 0; kc < 4; ++kc) aA[kc] = w1p[(size_t)(nA * 4 + kc) * 64 + lane];
    b1A = ((const float4*)(b1 + nA * HIDN))[q];
    w2A = ((const float4*)(w2 + nA * HIDN))[q];
    b2A = b2[nA];
    {
        int nB = nA + 12;
#pragma unroll
        for (int kc = 0; kc < 4; ++kc) aB[kc] = w1p[(size_t)(nB * 4 + kc) * 64 + lane];
        b1B = ((const float4*)(b1 + nB * HIDN))[q];
        w2B = ((const float4*)(w2 + nB * HIDN))[q];
        b2B = b2[nB];
    }

// One node: 16 MFMA -> f32 relu-FMA partials -> prefetch -> butterfly -> sigmoid -> LDS.
// Butterfly: lane(q,b) ends with logit of tile t==q, batch row q*16+b == lane.
#define MLP_BODY(AS, B1S, W2S, B2S, NODE, PREN)                                            \
    do {                                                                                   \
        float4v acc0 = {B1S.x, B1S.y, B1S.z, B1S.w};                                       \
        float4v acc1 = acc0, acc2 = acc0, acc3 = acc0;                                     \
        _Pragma("unroll") for (int kc = 0; kc < 4; ++kc) {                                 \
            acc0 = __builtin_amdgcn_mfma_f32_16x16x32_f16(AS[kc], bq[0][kc], acc0, 0, 0, 0);\
            acc1 = __builtin_amdgcn_mfma_f32_16x16x32_f16(AS[kc], bq[1][kc], acc1, 0, 0, 0);\
            acc2 = __builtin_amdgcn_mfma_f32_16x16x32_f16(AS[kc], bq[2][kc], acc2, 0, 0, 0);\
            acc3 = __builtin_amdgcn_mfma_f32_16x16x32_f16(AS[kc], bq[3][kc], acc3, 0, 0, 0);\
        }                                                                                  \
        float s0 = fmaf(fmaxf(acc0[0], 0.f), W2S.x, fmaf(fmaxf(acc0[1], 0.f), W2S.y,       \
                   fmaf(fmaxf(acc0[2], 0.f), W2S.z, fmaxf(acc0[3], 0.f) * W2S.w)));        \
        float s1 = fmaf(fmaxf(acc1[0], 0.f), W2S.x, fmaf(fmaxf(acc1[1], 0.f), W2S.y,       \
                   fmaf(fmaxf(acc1[2], 0.f), W2S.z, fmaxf(acc1[3], 0.f) * W2S.w)));        \
        float s2 = fmaf(fmaxf(acc2[0], 0.f), W2S.x, fmaf(fmaxf(acc2[1], 0.f), W2S.y,       \
                   fmaf(fmaxf(acc2[2], 0.f), W2S.z, fmaxf(acc2[3], 0.f) * W2S.w)));        \
        float s3 = fmaf(fmaxf(acc3[0], 0.f), W2S.x, fmaf(fmaxf(acc3[1], 0.f), W2S.y,       \
                   fmaf(fmaxf(acc3[2], 0.f), W2S.z, fmaxf(acc3[3], 0.f) * W2S.w)));        \
        float b2c = B2S;                                                                   \
        _Pragma("unroll") for (int kc = 0; kc < 4; ++kc)                                   \
            AS[kc] = w1p[(size_t)((PREN) * 4 + kc) * 64 + lane];                           \
        B1S = ((const float4*)(b1 + (PREN) * HIDN))[q];                                    \
        W2S = ((const float4*)(w2 + (PREN) * HIDN))[q];                                    \
        B2S = b2[PREN];                                                                    \
        int q1 = q & 1, q2 = q & 2;                                                        \
        float a01 = q1 ? s1 : s0, c01 = q1 ? s0 : s1;                                      \
        a01 += __shfl_xor(c01, 16, 64);                                                    \
        float a23 = q1 ? s3 : s2, c23 = q1 ? s2 : s3;                                      \
        a23 += __shfl_xor(c23, 16, 64);                                                    \
        float e = q2 ? a23 : a01, f = q2 ? a01 : a23;                                      \
        e += __shfl_xor(f, 32, 64);                                                        \
        float lg = e + b2c;                                                                \
        sp[lane][NODE] =                                                                   \
            __builtin_amdgcn_rcpf(1.f + __builtin_amdgcn_exp2f(-1.44269504088896f * lg));  \
    } while (0)

    // 11 ping-pong iterations cover nodes {wv + 12j, j=0..21}; indices past 254
    // clamp to 254 (recomputed with node-254's own operands -> identical value).
    for (int ii = 0; ii < 11; ++ii) {
        int pA = nA + 24; pA = pA > 254 ? 254 : pA;
        MLP_BODY(aA, b1A, w2A, b2A, nA, pA);          // nA <= 252 always
        int nB = nA + 12; nB = nB > 254 ? 254 : nB;
        int pB = nA + 36; pB = pB > 254 ? 254 : pB;
        MLP_BODY(aB, b1B, w2B, b2B, nB, pB);
        nA += 24;
    }
#undef MLP_BODY
    __syncthreads();

    // ---- phase 2: tree scan, rows r = wv, wv+12, ... straight from LDS ----
    const float4 lf = *(const float4*)(leaf + 4 * lane);
    for (int r = wv; r < 64; r += 12) {
        int b = blockIdx.x * 64 + r;
        const float* P = &sp[r][0];
        float* nr = nr_out + (size_t)b * NNODE;

        // p_out copy, coalesced
#pragma unroll
        for (int c = 0; c < 4; ++c) {
            int idx = c * 64 + lane;
            if (idx < NNODE)
                p_out[(size_t)b * NNODE + idx] = P[idx];
        }

        float pref = 1.f;
#pragma unroll
        for (int l = 0; l < 6; ++l) {
            if ((lane & ((1 << (6 - l)) - 1)) == 0)
                nr[(1 << l) - 1 + (lane >> (6 - l))] = pref;
            float pv  = P[(1 << l) - 1 + (lane >> (6 - l))];
            int  bit  = (lane >> (5 - l)) & 1;
            pref *= bit ? pv : (1.f - pv);
        }
        nr[63 + lane] = pref;
        float p6 = P[63 + lane];
        float pl = pref * (1.f - p6);
        float pr = pref * p6;
        nr[127 + 2 * lane] = pl;
        nr[128 + 2 * lane] = pr;
        float p7a = P[127 + 2 * lane];
        float p7b = P[128 + 2 * lane];
        float4v pp;
        pp[0] = pl * (1.f - p7a);
        pp[1] = pl * p7a;
        pp[2] = pr * (1.f - p7b);
        pp[3] = pr * p7b;
        *(float4v*)(pp_out + (size_t)b * NLEAF + 4 * lane) = pp;
        float hs = pp[0] * lf.x + pp[1] * lf.y + pp[2] * lf.z + pp[3] * lf.w;
#pragma unroll
        for (int off = 1; off < 64; off <<= 1) hs += __shfl_xor(hs, off, 64);
        if (lane == 0) h_out[b] = hs;
    }
}

extern "C" void kernel_launch(void* const* d_in, const int* in_sizes, int n_in,
                              void* d_out, int out_size, void* d_ws, size_t ws_size,
                              hipStream_t stream) {
    const float* x    = (const float*)d_in[0];
    const float* W1   = (const float*)d_in[1];
    const float* b1   = (const float*)d_in[2];
    const float* W2   = (const float*)d_in[3];
    const float* b2   = (const float*)d_in[4];
    const float* leaf = (const float*)d_in[5];

    float* out    = (float*)d_out;
    float* h_out  = out;                                   // [16384]
    float* pp_out = out + BATCH;                           // [16384*256]
    float* p_out  = pp_out + (size_t)BATCH * NLEAF;        // [16384*255]
    float* nr_out = p_out + (size_t)BATCH * NNODE;         // [16384*255]

    // workspace: 4 MB xp + ~1 MB w1p
    half8* xp  = (half8*)d_ws;
    half8* w1p = xp + (size_t)1024 * 4 * 64;

    hipLaunchKernelGGL(k_pack,  dim3(1024 + NNODE), dim3(256), 0, stream, x, W1, xp, w1p);
    hipLaunchKernelGGL(k_fused, dim3(256),          dim3(768), 0, stream,
                       xp, w1p, b1, W2, b2, leaf, h_out, pp_out, p_out, nr_out);
}